// Round 1
// 1636.306 us; speedup vs baseline: 1.6949x; 1.6949x over previous
//
#include <hip/hip_runtime.h>
#include <math.h>

#define BEHN 3
#define HN 64
#define SN 262144
#define NUSERS 1000000
#define BN_EPS 1e-5f

typedef __attribute__((ext_vector_type(8)))  short short8;
typedef __attribute__((ext_vector_type(16))) float f32x16;

union U4S8 { uint4 u; short8 s; };

__device__ __forceinline__ float sigmoidf_(float x) {
    return 1.f / (1.f + __expf(-x));
}

// split a pair of floats into packed bf16 hi (truncation) and bf16 lo (residual)
__device__ __forceinline__ void split2(float a, float b, unsigned* hi, unsigned* lo) {
    const unsigned ua = __float_as_uint(a), ub = __float_as_uint(b);
    *hi = (ua >> 16) | (ub & 0xFFFF0000u);
    const float ra = a - __uint_as_float(ua & 0xFFFF0000u);
    const float rb = b - __uint_as_float(ub & 0xFFFF0000u);
    *lo = (__float_as_uint(ra) >> 16) | (__float_as_uint(rb) & 0xFFFF0000u);
}

// gather 8 consecutive floats from rowp+off, split to hi/lo bf16 fragments
__device__ __forceinline__ void gather_kt(const float* __restrict__ rowp, int off,
                                          short8* ah, short8* al) {
    const float4 f0 = *(const float4*)(rowp + off);
    const float4 f1 = *(const float4*)(rowp + off + 4);
    U4S8 h, l;
    split2(f0.x, f0.y, &h.u.x, &l.u.x);
    split2(f0.z, f0.w, &h.u.y, &l.u.y);
    split2(f1.x, f1.y, &h.u.z, &l.u.z);
    split2(f1.z, f1.w, &h.u.w, &l.u.w);
    *ah = h.s; *al = l.s;
}

// Stage B^T[n][k] (n = output col 0..95 = W1 rows, col 96 = W3, 97..127 = 0)
// as bf16 hi/lo, XOR-swizzled in 16B units: phys_unit = u ^ (n&7).
__device__ void stage_B(const float* __restrict__ W1, const float* __restrict__ W3,
                        int w3len, uint4* Bhi, uint4* Blo, int tid) {
    for (int t = tid; t < 128 * 16; t += 256) {
        const int n = t >> 4, u = t & 15;
        float f[8];
        if (n < 96) {
            const float* p = W1 + n * 192 + 64 + u * 8;
            const float4 a = *(const float4*)p, b = *(const float4*)(p + 4);
            f[0]=a.x; f[1]=a.y; f[2]=a.z; f[3]=a.w;
            f[4]=b.x; f[5]=b.y; f[6]=b.z; f[7]=b.w;
        } else if (n == 96) {
            #pragma unroll
            for (int j = 0; j < 8; ++j) {
                const int k = u * 8 + j;
                f[j] = (k < w3len) ? W3[k] : 0.f;
            }
        } else {
            #pragma unroll
            for (int j = 0; j < 8; ++j) f[j] = 0.f;
        }
        U4S8 h, l;
        split2(f[0], f[1], &h.u.x, &l.u.x);
        split2(f[2], f[3], &h.u.y, &l.u.y);
        split2(f[4], f[5], &h.u.z, &l.u.z);
        split2(f[6], f[7], &h.u.w, &l.u.w);
        const int phys = (n << 4) | (u ^ (n & 7));
        Bhi[phys] = h.u;
        Blo[phys] = l.u;
    }
}

__device__ __forceinline__ short8 readB(const uint4* B, int n, int kt, int g, int c7) {
    const int u = (kt * 2 + g) ^ c7;
    return *(const short8*)&B[(n << 4) | u];
}

__global__ void init_kernel(float* stats) {
    if (threadIdx.x < 24) stats[threadIdx.x] = 0.f;
}

// ---------------- SSL: e = [ue_i[step_idx], u[step_idx]]; loss-block folded as loss*c1[j].
// t1 = sum_j w2[j]*prelu(C[s,j] + loss*c1[j] + b1[j]);  t3 = prelu(loss*C[s,96] + b3)
__global__ __launch_bounds__(256, 2)
void ssl_kernel(const float* __restrict__ infoNCE,      // [3,S]
                const int* __restrict__ step_idx,       // [S]
                const float* __restrict__ user_embeds,  // [3,N,H]
                const float* __restrict__ user_embed,   // [N,H]
                const float* __restrict__ W1,           // [96,192]
                const float* __restrict__ b1,           // [96]
                const float* __restrict__ W2,           // [96]
                const float* __restrict__ W3,           // [128]
                const float* __restrict__ b3p,          // [1]
                const float* __restrict__ prelu_ap,     // [1]
                float* __restrict__ tbuf,
                float* __restrict__ stats)
{
    __shared__ uint4 Bhi[128 * 16];   // 32 KB
    __shared__ uint4 Blo[128 * 16];   // 32 KB
    __shared__ float lc1[96], lb1[96], lw2[96];
    __shared__ float s_sum[6], s_sq[6];
    const int tid = threadIdx.x;

    stage_B(W1, W3, 128, Bhi, Blo, tid);
    for (int t = tid; t < 96; t += 256) {
        float sacc = 0.f;
        const float* row = W1 + t * 192;
        #pragma unroll
        for (int k = 0; k < 64; ++k) sacc += row[k];
        lc1[t] = sacc; lb1[t] = b1[t]; lw2[t] = W2[t];
    }
    if (tid < 6) { s_sum[tid] = 0.f; s_sq[tid] = 0.f; }
    __syncthreads();

    const int lane = tid & 63;
    const int wid  = tid >> 6;
    const int c = lane & 31;          // A row (sample-in-tile) / B col-in-tile
    const int g = lane >> 5;          // k half
    const int c7 = c & 7;
    const int s0 = blockIdx.x * 128 + wid * 32;
    const int sm = s0 + c;            // this lane's sample

    const float pa = prelu_ap[0];
    const float b3 = b3p[0];

    // per-lane epilogue constants (n = nt*32 + c)
    float c1v[3], b1v[3], w2v[3];
    #pragma unroll
    for (int nt = 0; nt < 3; ++nt) {
        c1v[nt] = lc1[nt * 32 + c];
        b1v[nt] = lb1[nt * 32 + c];
        w2v[nt] = lw2[nt * 32 + c];
    }

    const int idx = step_idx[sm];
    const float* e1p = user_embed + (size_t)idx * HN;

    short8 ah[8], al[8];
    #pragma unroll
    for (int kt = 0; kt < 4; ++kt)   // shared u-row: k 64..127 -> kt 4..7
        gather_kt(e1p, kt * 16 + g * 8, &ah[4 + kt], &al[4 + kt]);

    #pragma unroll 1
    for (int i = 0; i < BEHN; ++i) {
        const float* e0p = user_embeds + ((size_t)i * NUSERS + (size_t)idx) * HN;
        #pragma unroll
        for (int kt = 0; kt < 4; ++kt)
            gather_kt(e0p, kt * 16 + g * 8, &ah[kt], &al[kt]);

        const float Lm = infoNCE[(size_t)i * SN + sm];
        float lossr[16];
        #pragma unroll
        for (int r = 0; r < 16; ++r) {
            const int m = (r & 3) + 8 * (r >> 2) + 4 * g;
            lossr[r] = __shfl(Lm, m, 64);
        }

        f32x16 acc[4];
        #pragma unroll
        for (int nt = 0; nt < 4; ++nt)
            #pragma unroll
            for (int q = 0; q < 16; ++q) acc[nt][q] = 0.f;

        #pragma unroll
        for (int kt = 0; kt < 8; ++kt) {
            #pragma unroll
            for (int nt = 0; nt < 4; ++nt) {
                const short8 bh = readB(Bhi, nt * 32 + c, kt, g, c7);
                const short8 bl = readB(Blo, nt * 32 + c, kt, g, c7);
                acc[nt] = __builtin_amdgcn_mfma_f32_32x32x16_bf16(ah[kt], bh, acc[nt], 0, 0, 0);
                acc[nt] = __builtin_amdgcn_mfma_f32_32x32x16_bf16(al[kt], bh, acc[nt], 0, 0, 0);
                acc[nt] = __builtin_amdgcn_mfma_f32_32x32x16_bf16(ah[kt], bl, acc[nt], 0, 0, 0);
            }
        }

        // t1 partials: this lane covers n = {c, 32+c, 64+c}
        float t1p[16];
        #pragma unroll
        for (int r = 0; r < 16; ++r) {
            float t = 0.f;
            #pragma unroll
            for (int nt = 0; nt < 3; ++nt) {
                float h = acc[nt][r] + lossr[r] * c1v[nt] + b1v[nt];
                h = h >= 0.f ? h : pa * h;
                t = fmaf(w2v[nt], h, t);
            }
            t1p[r] = t;
        }
        #pragma unroll
        for (int off = 1; off < 32; off <<= 1)
            #pragma unroll
            for (int r = 0; r < 16; ++r)
                t1p[r] += __shfl_xor(t1p[r], off, 64);

        if (c == 0) {   // lanes 0 and 32: hold col 96 (t3) and full t1 sums
            float s1 = 0.f, q1 = 0.f, s3 = 0.f, q3 = 0.f;
            #pragma unroll
            for (int r = 0; r < 16; ++r) {
                const int m = (r & 3) + 8 * (r >> 2) + 4 * g;
                float v = fmaf(lossr[r], acc[3][r], b3);
                v = v >= 0.f ? v : pa * v;
                tbuf[(size_t)i * SN + s0 + m] = t1p[r];
                tbuf[(size_t)(3 + i) * SN + s0 + m] = v;
                s1 += t1p[r]; q1 = fmaf(t1p[r], t1p[r], q1);
                s3 += v;      q3 = fmaf(v, v, q3);
            }
            atomicAdd(&s_sum[i], s1);     atomicAdd(&s_sq[i], q1);
            atomicAdd(&s_sum[3 + i], s3); atomicAdd(&s_sq[3 + i], q3);
        }
    }
    __syncthreads();
    if (tid < 6) {
        atomicAdd(stats + tid, s_sum[tid]);
        atomicAdd(stats + 12 + tid, s_sq[tid]);
    }
}

// ---------------- RS: e = [u[ridx], ue_i[ridx]]; col 96 = W3 (k<64) else 0.
__global__ __launch_bounds__(256, 2)
void rs_kernel(const float* __restrict__ bloss_list,   // [3,S]
               const int* __restrict__ uidx_list,      // [3,S]
               const float* __restrict__ user_embeds,  // [3,N,H]
               const float* __restrict__ user_embed,   // [N,H]
               const float* __restrict__ W1,           // [96,192]
               const float* __restrict__ b1,           // [96]
               const float* __restrict__ W2,           // [96]
               const float* __restrict__ W3,           // [64]
               const float* __restrict__ b3p,
               const float* __restrict__ prelu_ap,
               float* __restrict__ tbuf,
               float* __restrict__ stats)
{
    __shared__ uint4 Bhi[128 * 16];
    __shared__ uint4 Blo[128 * 16];
    __shared__ float lc1[96], lb1[96], lw2[96];
    __shared__ float s_sum[6], s_sq[6];
    const int tid = threadIdx.x;

    stage_B(W1, W3, 64, Bhi, Blo, tid);
    for (int t = tid; t < 96; t += 256) {
        float sacc = 0.f;
        const float* row = W1 + t * 192;
        #pragma unroll
        for (int k = 0; k < 64; ++k) sacc += row[k];
        lc1[t] = sacc; lb1[t] = b1[t]; lw2[t] = W2[t];
    }
    if (tid < 6) { s_sum[tid] = 0.f; s_sq[tid] = 0.f; }
    __syncthreads();

    const int lane = tid & 63;
    const int wid  = tid >> 6;
    const int c = lane & 31;
    const int g = lane >> 5;
    const int c7 = c & 7;
    const int s0 = blockIdx.x * 128 + wid * 32;
    const int sm = s0 + c;

    const float pa = prelu_ap[0];
    const float b3 = b3p[0];

    float c1v[3], b1v[3], w2v[3];
    #pragma unroll
    for (int nt = 0; nt < 3; ++nt) {
        c1v[nt] = lc1[nt * 32 + c];
        b1v[nt] = lb1[nt * 32 + c];
        w2v[nt] = lw2[nt * 32 + c];
    }

    #pragma unroll 1
    for (int i = 0; i < BEHN; ++i) {
        const int idx = uidx_list[(size_t)i * SN + sm];
        const float* e0p = user_embed + (size_t)idx * HN;                              // u_r: k 0..63
        const float* e1p = user_embeds + ((size_t)i * NUSERS + (size_t)idx) * HN;      // ue_i_r: k 64..127
        short8 ah[8], al[8];
        #pragma unroll
        for (int kt = 0; kt < 4; ++kt) {
            gather_kt(e0p, kt * 16 + g * 8, &ah[kt], &al[kt]);
            gather_kt(e1p, kt * 16 + g * 8, &ah[4 + kt], &al[4 + kt]);
        }

        const float Lm = bloss_list[(size_t)i * SN + sm];
        float lossr[16];
        #pragma unroll
        for (int r = 0; r < 16; ++r) {
            const int m = (r & 3) + 8 * (r >> 2) + 4 * g;
            lossr[r] = __shfl(Lm, m, 64);
        }

        f32x16 acc[4];
        #pragma unroll
        for (int nt = 0; nt < 4; ++nt)
            #pragma unroll
            for (int q = 0; q < 16; ++q) acc[nt][q] = 0.f;

        #pragma unroll
        for (int kt = 0; kt < 8; ++kt) {
            #pragma unroll
            for (int nt = 0; nt < 4; ++nt) {
                const short8 bh = readB(Bhi, nt * 32 + c, kt, g, c7);
                const short8 bl = readB(Blo, nt * 32 + c, kt, g, c7);
                acc[nt] = __builtin_amdgcn_mfma_f32_32x32x16_bf16(ah[kt], bh, acc[nt], 0, 0, 0);
                acc[nt] = __builtin_amdgcn_mfma_f32_32x32x16_bf16(al[kt], bh, acc[nt], 0, 0, 0);
                acc[nt] = __builtin_amdgcn_mfma_f32_32x32x16_bf16(ah[kt], bl, acc[nt], 0, 0, 0);
            }
        }

        float t1p[16];
        #pragma unroll
        for (int r = 0; r < 16; ++r) {
            float t = 0.f;
            #pragma unroll
            for (int nt = 0; nt < 3; ++nt) {
                float h = acc[nt][r] + lossr[r] * c1v[nt] + b1v[nt];
                h = h >= 0.f ? h : pa * h;
                t = fmaf(w2v[nt], h, t);
            }
            t1p[r] = t;
        }
        #pragma unroll
        for (int off = 1; off < 32; off <<= 1)
            #pragma unroll
            for (int r = 0; r < 16; ++r)
                t1p[r] += __shfl_xor(t1p[r], off, 64);

        if (c == 0) {
            float s1 = 0.f, q1 = 0.f, s3 = 0.f, q3 = 0.f;
            #pragma unroll
            for (int r = 0; r < 16; ++r) {
                const int m = (r & 3) + 8 * (r >> 2) + 4 * g;
                float v = fmaf(lossr[r], acc[3][r], b3);
                v = v >= 0.f ? v : pa * v;
                tbuf[(size_t)(6 + i) * SN + s0 + m] = t1p[r];
                tbuf[(size_t)(9 + i) * SN + s0 + m] = v;
                s1 += t1p[r]; q1 = fmaf(t1p[r], t1p[r], q1);
                s3 += v;      q3 = fmaf(v, v, q3);
            }
            atomicAdd(&s_sum[i], s1);     atomicAdd(&s_sq[i], q1);
            atomicAdd(&s_sum[3 + i], s3); atomicAdd(&s_sq[3 + i], q3);
        }
    }
    __syncthreads();
    if (tid < 6) {
        atomicAdd(stats + 6 + tid, s_sum[tid]);
        atomicAdd(stats + 18 + tid, s_sq[tid]);
    }
}

__global__ void stats_kernel(const float* __restrict__ stats, float* __restrict__ mi) {
    const int a = threadIdx.x;
    if (a < 12) {
        const float inv_n = 1.f / (float)SN;
        const float mean = stats[a] * inv_n;
        float var = stats[12 + a] * inv_n - mean * mean;
        var = fmaxf(var, 0.f);
        mi[a] = mean;
        mi[12 + a] = rsqrtf(var + BN_EPS);
    }
}

__global__ __launch_bounds__(256)
void final_kernel(const float* __restrict__ tbuf, const float* __restrict__ mi,
                  float* __restrict__ out)
{
    const int x = blockIdx.x * 256 + threadIdx.x;  // < 3*SN
    const int i = x / SN;
    const int s = x - i * SN;
    const float w1 = sigmoidf_((tbuf[(size_t)i * SN + s]       - mi[i])     * mi[12 + i]);
    const float w3 = sigmoidf_((tbuf[(size_t)(3 + i) * SN + s] - mi[3 + i]) * mi[12 + 3 + i]);
    const float r1 = sigmoidf_((tbuf[(size_t)(6 + i) * SN + s] - mi[6 + i]) * mi[12 + 6 + i]);
    const float r3 = sigmoidf_((tbuf[(size_t)(9 + i) * SN + s] - mi[9 + i]) * mi[12 + 9 + i]);
    out[(size_t)i * SN + s] = 0.5f * (w1 + w3);
    out[(size_t)3 * SN + (size_t)i * SN + s] = r1 + r3;
}

extern "C" void kernel_launch(void* const* d_in, const int* in_sizes, int n_in,
                              void* d_out, int out_size, void* d_ws, size_t ws_size,
                              hipStream_t stream) {
    (void)in_sizes; (void)n_in; (void)out_size; (void)ws_size;
    const float* infoNCE = (const float*)d_in[0];
    const float* bloss   = (const float*)d_in[1];
    const int*   stepidx = (const int*)d_in[2];
    const int*   uidx    = (const int*)d_in[3];
    const float* uembs   = (const float*)d_in[4];
    const float* uemb    = (const float*)d_in[5];
    const float* W_ssl1  = (const float*)d_in[6];
    const float* b_ssl1  = (const float*)d_in[7];
    const float* W_ssl2  = (const float*)d_in[8];
    // d_in[9] = b_ssl2: cancels inside BN (pure shift)
    const float* W_ssl3  = (const float*)d_in[10];
    const float* b_ssl3  = (const float*)d_in[11];
    const float* W_rs1   = (const float*)d_in[12];
    const float* b_rs1   = (const float*)d_in[13];
    const float* W_rs2   = (const float*)d_in[14];
    // d_in[15] = b_rs2: cancels inside BN
    const float* W_rs3   = (const float*)d_in[16];
    const float* b_rs3   = (const float*)d_in[17];
    const float* pa      = (const float*)d_in[18];

    float* tbuf  = (float*)d_ws;                    // 12 * SN floats
    float* stats = tbuf + (size_t)12 * SN;          // 24 floats (sum[12], sumsq[12])
    float* mi    = stats + 24;                      // 24 floats (mean[12], inv[12])
    float* out   = (float*)d_out;

    hipLaunchKernelGGL(init_kernel, dim3(1), dim3(64), 0, stream, stats);
    hipLaunchKernelGGL(ssl_kernel, dim3(SN / 128), dim3(256), 0, stream,
                       infoNCE, stepidx, uembs, uemb,
                       W_ssl1, b_ssl1, W_ssl2, W_ssl3, b_ssl3, pa, tbuf, stats);
    hipLaunchKernelGGL(rs_kernel, dim3(SN / 128), dim3(256), 0, stream,
                       bloss, uidx, uembs, uemb,
                       W_rs1, b_rs1, W_rs2, W_rs3, b_rs3, pa, tbuf, stats);
    hipLaunchKernelGGL(stats_kernel, dim3(1), dim3(64), 0, stream, stats, mi);
    hipLaunchKernelGGL(final_kernel, dim3((3 * SN) / 256), dim3(256), 0, stream, tbuf, mi, out);
}